// Round 1
// baseline (125.366 us; speedup 1.0000x reference)
//
#include <hip/hip_runtime.h>

// 3D Laplacian, 7-point stencil, zero ("same") padding.
// x: [B=16, 1, NX=256, NY=128, NZ=64] float32, z contiguous.

#define NB 16
#define NX 256
#define NY 128
#define NZ 64

// Compile-time constants in double, truncated to f32 (matches jnp.asarray(c, f32)).
constexpr double DXD = 6.3 / (NX - 1);
constexpr double DYD = 3.1 / (NY - 1);
constexpr double DZD = 1.5 / (NZ - 1);
constexpr float FCX = (float)(1.0 / (DXD * DXD));
constexpr float FCY = (float)(1.0 / (DYD * DYD));
constexpr float FCZ = (float)(1.0 / (DZD * DZD));
constexpr float FCC = (float)(-2.0 * (1.0 / (DXD * DXD) + 1.0 / (DYD * DYD) + 1.0 / (DZD * DZD)));

// Block: 256 threads = 16 z-quads (float4) x 16 y-rows.
// Grid: (NY/16, NX, NB).
__global__ __launch_bounds__(256) void lap3d_kernel(const float4* __restrict__ in,
                                                    float4* __restrict__ out) {
    const int t  = threadIdx.x;
    const int z4 = t & 15;        // which float4 along z (z = z4*4 .. z4*4+3)
    const int ly = t >> 4;        // local y row
    const int y  = blockIdx.x * 16 + ly;
    const int x  = blockIdx.y;
    const int b  = blockIdx.z;

    const int row = (b * NX + x) * NY + y;   // row index in units of z-rows
    const int ctr = row * (NZ / 4) + z4;     // index in float4 units

    const float4 zero = make_float4(0.f, 0.f, 0.f, 0.f);
    const float4 c  = in[ctr];
    const float4 xm = (x > 0)      ? in[ctr - NY * (NZ / 4)] : zero;
    const float4 xp = (x < NX - 1) ? in[ctr + NY * (NZ / 4)] : zero;
    const float4 ym = (y > 0)      ? in[ctr - (NZ / 4)]      : zero;
    const float4 yp = (y < NY - 1) ? in[ctr + (NZ / 4)]      : zero;

    // z-edge neighbors from adjacent lanes within the wave. At lane-group
    // boundaries the shuffled value comes from a different y-row, but those
    // lanes are exactly z==0 / z==63 where the zero-padding overrides it.
    float zm = __shfl_up(c.w, 1);
    float zp = __shfl_down(c.x, 1);
    if (z4 == 0)  zm = 0.f;
    if (z4 == 15) zp = 0.f;

    float4 o;
    o.x = FCC * c.x + FCX * (xm.x + xp.x) + FCY * (ym.x + yp.x) + FCZ * (zm  + c.y);
    o.y = FCC * c.y + FCX * (xm.y + xp.y) + FCY * (ym.y + yp.y) + FCZ * (c.x + c.z);
    o.z = FCC * c.z + FCX * (xm.z + xp.z) + FCY * (ym.z + yp.z) + FCZ * (c.y + c.w);
    o.w = FCC * c.w + FCX * (xm.w + xp.w) + FCY * (ym.w + yp.w) + FCZ * (c.z + zp);

    out[ctr] = o;
}

extern "C" void kernel_launch(void* const* d_in, const int* in_sizes, int n_in,
                              void* d_out, int out_size, void* d_ws, size_t ws_size,
                              hipStream_t stream) {
    const float4* in  = (const float4*)d_in[0];
    float4*       out = (float4*)d_out;

    dim3 grid(NY / 16, NX, NB);
    dim3 block(256);
    lap3d_kernel<<<grid, block, 0, stream>>>(in, out);
}

// Round 2
// 45.687 us; speedup vs baseline: 2.7440x; 2.7440x over previous
//
#include <hip/hip_runtime.h>

// 3D Laplacian, 7-point stencil, zero ("same") padding.
// x: [B=16, 1, NX=256, NY=128, NZ=64] float32, z contiguous.
// Round 2: branchless clamped loads + 4 x-planes per thread for MLP.

#define NB 16
#define NX 256
#define NY 128
#define NZ 64
#define ZQ (NZ / 4)          // float4s per z-row = 16
#define PLANE (NY * ZQ)      // float4s per x-plane = 2048

constexpr double DXD = 6.3 / (NX - 1);
constexpr double DYD = 3.1 / (NY - 1);
constexpr double DZD = 1.5 / (NZ - 1);
constexpr float FCX = (float)(1.0 / (DXD * DXD));
constexpr float FCY = (float)(1.0 / (DYD * DYD));
constexpr float FCZ = (float)(1.0 / (DZD * DZD));
constexpr float FCC = (float)(-2.0 * (1.0 / (DXD * DXD) + 1.0 / (DYD * DYD) + 1.0 / (DZD * DZD)));

// Block: 256 threads = 16 z-quads x 16 y-rows. Each thread computes 4
// consecutive x-planes. Grid: (NY/16, NX/4, NB).
__global__ __launch_bounds__(256) void lap3d_kernel(const float4* __restrict__ in,
                                                    float4* __restrict__ out) {
    const int t  = threadIdx.x;
    const int z4 = t & 15;
    const int ly = t >> 4;
    const int y  = blockIdx.x * 16 + ly;
    const int x0 = blockIdx.y * 4;
    const int b  = blockIdx.z;

    const float4* bin  = in  + (size_t)b * NX * PLANE;
    float4*       bout = out + (size_t)b * NX * PLANE;
    const int rowoff = y * ZQ + z4;

    // Center column: planes x0-1 .. x0+4, clamped. 6 independent loads.
    float4 cc[6];
#pragma unroll
    for (int j = 0; j < 6; ++j) {
        int px = x0 - 1 + j;
        px = px < 0 ? 0 : (px > NX - 1 ? NX - 1 : px);
        cc[j] = bin[px * PLANE + rowoff];
    }

    // y-neighbors for planes x0..x0+3, rows clamped. 8 independent loads.
    const int ymr = (y > 0 ? y - 1 : 0) * ZQ + z4;
    const int ypr = (y < NY - 1 ? y + 1 : NY - 1) * ZQ + z4;
    float4 vym[4], vyp[4];
#pragma unroll
    for (int i = 0; i < 4; ++i) {
        vym[i] = bin[(x0 + i) * PLANE + ymr];
        vyp[i] = bin[(x0 + i) * PLANE + ypr];
    }

    const float myM = (y > 0)      ? FCY : 0.f;
    const float myP = (y < NY - 1) ? FCY : 0.f;

#pragma unroll
    for (int i = 0; i < 4; ++i) {
        const int   px  = x0 + i;
        const float fxm = (px > 0)      ? FCX : 0.f;
        const float fxp = (px < NX - 1) ? FCX : 0.f;

        const float4 c  = cc[i + 1];
        const float4 xm = cc[i];
        const float4 xp = cc[i + 2];

        // z-edge neighbors from adjacent lanes; lane-group boundary lanes are
        // exactly z==0 / z==63 where zero padding overrides the value.
        float zm = __shfl_up(c.w, 1);
        float zp = __shfl_down(c.x, 1);
        if (z4 == 0)  zm = 0.f;
        if (z4 == 15) zp = 0.f;

        float4 o;
        o.x = FCC * c.x + fxm * xm.x + fxp * xp.x + myM * vym[i].x + myP * vyp[i].x + FCZ * (zm  + c.y);
        o.y = FCC * c.y + fxm * xm.y + fxp * xp.y + myM * vym[i].y + myP * vyp[i].y + FCZ * (c.x + c.z);
        o.z = FCC * c.z + fxm * xm.z + fxp * xp.z + myM * vym[i].z + myP * vyp[i].z + FCZ * (c.y + c.w);
        o.w = FCC * c.w + fxm * xm.w + fxp * xp.w + myM * vym[i].w + myP * vyp[i].w + FCZ * (c.z + zp);

        bout[px * PLANE + rowoff] = o;
    }
}

extern "C" void kernel_launch(void* const* d_in, const int* in_sizes, int n_in,
                              void* d_out, int out_size, void* d_ws, size_t ws_size,
                              hipStream_t stream) {
    const float4* in  = (const float4*)d_in[0];
    float4*       out = (float4*)d_out;

    dim3 grid(NY / 16, NX / 4, NB);
    dim3 block(256);
    lap3d_kernel<<<grid, block, 0, stream>>>(in, out);
}

// Round 4
// 45.092 us; speedup vs baseline: 2.7803x; 1.0132x over previous
//
#include <hip/hip_runtime.h>

// 3D Laplacian, 7-point stencil, zero ("same") padding.
// x: [B=16, 1, NX=256, NY=128, NZ=64] float32, z contiguous.
// Round 4: nontemporal store via native clang vector type (HIP_vector_type
// isn't accepted by __builtin_nontemporal_store).

#define NB 16
#define NX 256
#define NY 128
#define NZ 64
#define ZQ (NZ / 4)          // float4s per z-row = 16
#define PLANE (NY * ZQ)      // float4s per x-plane = 2048

typedef float f32x4 __attribute__((ext_vector_type(4)));

constexpr double DXD = 6.3 / (NX - 1);
constexpr double DYD = 3.1 / (NY - 1);
constexpr double DZD = 1.5 / (NZ - 1);
constexpr float FCX = (float)(1.0 / (DXD * DXD));
constexpr float FCY = (float)(1.0 / (DYD * DYD));
constexpr float FCZ = (float)(1.0 / (DZD * DZD));
constexpr float FCC = (float)(-2.0 * (1.0 / (DXD * DXD) + 1.0 / (DYD * DYD) + 1.0 / (DZD * DZD)));

// Block: 256 threads = 16 z-quads x 16 y-rows. Each thread computes 4
// consecutive x-planes. Grid: (NY/16, NX/4, NB).
__global__ __launch_bounds__(256) void lap3d_kernel(const float4* __restrict__ in,
                                                    float4* __restrict__ out) {
    const int t  = threadIdx.x;
    const int z4 = t & 15;
    const int ly = t >> 4;
    const int y  = blockIdx.x * 16 + ly;
    const int x0 = blockIdx.y * 4;
    const int b  = blockIdx.z;

    const float4* bin  = in  + (size_t)b * NX * PLANE;
    float4*       bout = out + (size_t)b * NX * PLANE;
    const int rowoff = y * ZQ + z4;

    // Center column: planes x0-1 .. x0+4, clamped. 6 independent loads.
    float4 cc[6];
#pragma unroll
    for (int j = 0; j < 6; ++j) {
        int px = x0 - 1 + j;
        px = px < 0 ? 0 : (px > NX - 1 ? NX - 1 : px);
        cc[j] = bin[px * PLANE + rowoff];
    }

    // y-neighbors for planes x0..x0+3, rows clamped. 8 independent loads.
    const int ymr = (y > 0 ? y - 1 : 0) * ZQ + z4;
    const int ypr = (y < NY - 1 ? y + 1 : NY - 1) * ZQ + z4;
    float4 vym[4], vyp[4];
#pragma unroll
    for (int i = 0; i < 4; ++i) {
        vym[i] = bin[(x0 + i) * PLANE + ymr];
        vyp[i] = bin[(x0 + i) * PLANE + ypr];
    }

    const float myM = (y > 0)      ? FCY : 0.f;
    const float myP = (y < NY - 1) ? FCY : 0.f;

#pragma unroll
    for (int i = 0; i < 4; ++i) {
        const int   px  = x0 + i;
        const float fxm = (px > 0)      ? FCX : 0.f;
        const float fxp = (px < NX - 1) ? FCX : 0.f;

        const float4 c  = cc[i + 1];
        const float4 xm = cc[i];
        const float4 xp = cc[i + 2];

        // z-edge neighbors from adjacent lanes; lane-group boundary lanes are
        // exactly z==0 / z==63 where zero padding overrides the value.
        float zm = __shfl_up(c.w, 1);
        float zp = __shfl_down(c.x, 1);
        if (z4 == 0)  zm = 0.f;
        if (z4 == 15) zp = 0.f;

        f32x4 o;
        o.x = FCC * c.x + fxm * xm.x + fxp * xp.x + myM * vym[i].x + myP * vyp[i].x + FCZ * (zm  + c.y);
        o.y = FCC * c.y + fxm * xm.y + fxp * xp.y + myM * vym[i].y + myP * vyp[i].y + FCZ * (c.x + c.z);
        o.z = FCC * c.z + fxm * xm.z + fxp * xp.z + myM * vym[i].z + myP * vyp[i].z + FCZ * (c.y + c.w);
        o.w = FCC * c.w + fxm * xm.w + fxp * xp.w + myM * vym[i].w + myP * vyp[i].w + FCZ * (c.z + zp);

        // Output has zero reuse: stream it past L2/L3 so the input stays
        // L3-resident (input+output = 256 MB = exactly L3 capacity).
        __builtin_nontemporal_store(o, (f32x4*)&bout[px * PLANE + rowoff]);
    }
}

extern "C" void kernel_launch(void* const* d_in, const int* in_sizes, int n_in,
                              void* d_out, int out_size, void* d_ws, size_t ws_size,
                              hipStream_t stream) {
    const float4* in  = (const float4*)d_in[0];
    float4*       out = (float4*)d_out;

    dim3 grid(NY / 16, NX / 4, NB);
    dim3 block(256);
    lap3d_kernel<<<grid, block, 0, stream>>>(in, out);
}